// Round 7
// baseline (111.433 us; speedup 1.0000x reference)
//
#include <hip/hip_runtime.h>
#include <math.h>

#define NN 257
#define NN2 66049        // 257*257
#define PROW 260         // padded psf row stride (floats), 16B-aligned rows
#define PCH (PROW * NN)  // floats per psf channel
#define NRZ 15           // psf-row chunks (15 * 9 = 135 rows per y-tile)
#define FSW 288          // swizzled flipped-psf row size

// granule swizzle: f multiple of 4 -> swizzled float offset (keeps 16B granules intact)
#define SWG(f) (((((f) >> 2) ^ (((f) >> 5) & 7)) << 2))
#define SW(f) (SWG(f) | ((f) & 3))

static const double D_PI = 3.14159265358979323846;

__device__ __forceinline__ double lam_of(int c) {
    return c == 0 ? 610e-9 : (c == 1 ? 530e-9 : 470e-9);
}

// fast accurate phase: exp(i*2*pi*rev), rev = dist/lam computed in f64, frac -> f32 hw sincos
__device__ __forceinline__ float2 phase_of(double rev) {
    rev -= floor(rev);
    float ang = (float)(2.0 * D_PI * rev);
    float sv, cv;
    __sincosf(ang, &sv, &cv);
    return make_float2(cv, sv);
}

// ---------------- kernel 1: depth mean (blk 0) + img transpose (blk 1..192) + twiddle table (blk 193) ----------------
__global__ __launch_bounds__(256) void k_prep(const float* __restrict__ depth, const float* __restrict__ img,
                                              double* zs, float* __restrict__ imgp, float2* __restrict__ twg) {
    if (blockIdx.x == 0) {
        __shared__ double s[256];
        double acc = 0.0;
        for (int i = threadIdx.x; i < 16384; i += 256) acc += (double)depth[i];
        s[threadIdx.x] = acc;
        __syncthreads();
        for (int o = 128; o > 0; o >>= 1) {
            if (threadIdx.x < o) s[threadIdx.x] += s[threadIdx.x + o];
            __syncthreads();
        }
        if (threadIdx.x == 0) {
            zs[0] = s[0] / 16384.0;
            zs[1] = 0.0; zs[2] = 0.0; zs[3] = 0.0;
        }
    } else if (blockIdx.x == 193) {
        int m = threadIdx.x;
        double th = 2.0 * D_PI * (double)m / 257.0;
        double sv, cv; sincos(th, &sv, &cv);
        twg[m] = make_float2((float)cv, (float)(-sv));   // exp(-2*pi*i*m/257)
        if (m == 0) {
            th = 2.0 * D_PI * 256.0 / 257.0;
            sincos(th, &sv, &cv);
            twg[256] = make_float2((float)cv, (float)(-sv));
        }
    } else {
        int idx = (blockIdx.x - 1) * 256 + threadIdx.x;  // < 49152
        int c = idx / 16384;
        int r = idx & 16383;
        imgp[c * 16384 + r] = img[r * 3 + c];
    }
}

// ---------------- DFT pass: out[c][b][a] = sum_t colval(t,b) * exp(SIGN*2*pi*i*a*t/257) ----------------
// Two b-columns per block (b0 = 2*by, b1 = b0+1; by==128 -> duplicate b=256, masked in sums).
// t-sum split 4 ways across thread quarters (t ≡ q mod 4); 64 a-values per block, a = ah*64 + (tid&63).
// a=256 output computed by full-block reduce in ah==3 blocks.
// MODE 0: colval generated analytically (fftshift'd aperture field), no input read
// MODE 1: colval = in[c][t][b]
// MODE 2: colval = in[c][t][b] * fftshift(H)(t,b)
// MODE 3: like 1; epilogue writes |.|^2/N^4 ifftshift'd into raw (padded planar) + channel sums
template <int SIGN, int MODE>
__global__ __launch_bounds__(256) void k_dft(const float2* __restrict__ in, float2* __restrict__ out,
                                             const float2* __restrict__ twg, const double* __restrict__ zs,
                                             float* __restrict__ raw, double* __restrict__ sums) {
    __shared__ float4 col[NN];       // {re0, im0, re1, im1}
    __shared__ float2 twL[NN];
    __shared__ float4 sacc[3][64];
    __shared__ float4 red[4];
    const int ah = blockIdx.x;       // a-quarter
    const int by = blockIdx.y;       // b-pair
    const int c = blockIdx.z;
    const int bc0 = 2 * by;
    const int bc1 = (bc0 < 256) ? bc0 + 1 : 256;
    const float dupf = (bc1 == bc0) ? 0.f : 1.f;
    const int tid = threadIdx.x;

    // ---- stage two columns (fused generation / H-multiply) ----
    for (int t = tid; t < NN; t += 256) {
        twL[t] = twg[t];
        float2 v0, v1;
        if (MODE == 0) {
            int js = t + 129; if (js >= NN) js -= NN;
            const double step = 0.01 / 256.0;
            double yy = -0.005 + js * step;
            double z1 = zs[0];
            double lam = lam_of(c);
            const double ap = 0.5 * (0.01 / 257.0) * 128.0 + 1e-7;
            {
                int is = bc0 + 129; if (is >= NN) is -= NN;
                double x = -0.005 + is * step;
                double r2 = x * x + yy * yy;
                v0 = make_float2(0.f, 0.f);
                if (sqrt(r2) <= ap) v0 = phase_of(sqrt(r2 + z1 * z1) / lam);
            }
            {
                int is = bc1 + 129; if (is >= NN) is -= NN;
                double x = -0.005 + is * step;
                double r2 = x * x + yy * yy;
                v1 = make_float2(0.f, 0.f);
                if (sqrt(r2) <= ap) v1 = phase_of(sqrt(r2 + z1 * z1) / lam);
            }
        } else {
            v0 = in[(c * NN + t) * NN + bc0];
            v1 = in[(c * NN + t) * NN + bc1];
            if (MODE == 2) {
                int ps = t + 129; if (ps >= NN) ps -= NN;
                const double fstep = 25700.0 / 256.0;
                double fy = -12850.0 + ps * fstep;
                double lam = lam_of(c);
                double ilam2 = 1.0 / (lam * lam);
                double kzr = 0.05 / lam;
                {
                    int qs = bc0 + 129; if (qs >= NN) qs -= NN;
                    double fx = -12850.0 + qs * fstep;
                    double lfx = lam * fx, lfy = lam * fy;
                    double a2 = 1.0 - lfx * lfx - lfy * lfy;
                    float2 hh = make_float2(0.f, 0.f);
                    if (fx * fx + fy * fy < ilam2) hh = phase_of(kzr * sqrt(a2 > 0.0 ? a2 : 0.0));
                    v0 = make_float2(v0.x * hh.x - v0.y * hh.y, v0.x * hh.y + v0.y * hh.x);
                }
                {
                    int qs = bc1 + 129; if (qs >= NN) qs -= NN;
                    double fx = -12850.0 + qs * fstep;
                    double lfx = lam * fx, lfy = lam * fy;
                    double a2 = 1.0 - lfx * lfx - lfy * lfy;
                    float2 hh = make_float2(0.f, 0.f);
                    if (fx * fx + fy * fy < ilam2) hh = phase_of(kzr * sqrt(a2 > 0.0 ? a2 : 0.0));
                    v1 = make_float2(v1.x * hh.x - v1.y * hh.y, v1.x * hh.y + v1.y * hh.x);
                }
            }
        }
        col[t] = make_float4(v0.x, v0.y, v1.x, v1.y);
    }
    __syncthreads();

    const float invn4 = (float)(1.0 / ((double)NN2 * (double)NN2));
    const int q = tid >> 6;          // t-quarter (t ≡ q mod 4)
    const int al = tid & 63;
    const int a = ah * 64 + al;      // output index 0..255 (256 via ah==3 reduce)

    // 4 twiddle chains: t = q + 4m + 16j, m=0..3, j=0..15; step multiplier omega^{16*a}
    // table: twL[m] = exp(-2*pi*i*m/257); omega^m = (twL[m].x, -SIGN*twL[m].y)
    float cxm[4], cym[4];
    #pragma unroll
    for (int m = 0; m < 4; ++m) {
        int sm = (a * (q + 4 * m)) % 257;
        float2 tt = twL[sm];
        cxm[m] = tt.x; cym[m] = -SIGN * tt.y;
    }
    int d16 = (16 * a) % 257;
    float2 w16 = twL[d16];
    const float wsx = w16.x, wsy = -SIGN * w16.y;

    float A0x = 0.f, A0y = 0.f, A1x = 0.f, A1y = 0.f;  // col bc0 (chains 0,1 / 2,3)
    float B0x = 0.f, B0y = 0.f, B1x = 0.f, B1y = 0.f;  // col bc1

    for (int j = 0; j < 16; ++j) {
        const int tbase = q + 16 * j;
        #pragma unroll
        for (int m = 0; m < 4; ++m) {
            float4 v = col[tbase + 4 * m];
            float cx = cxm[m], cy = cym[m];
            if (m < 2) {
                A0x = fmaf(v.x, cx, A0x); A0x = fmaf(-v.y, cy, A0x);
                A0y = fmaf(v.x, cy, A0y); A0y = fmaf(v.y, cx, A0y);
                B0x = fmaf(v.z, cx, B0x); B0x = fmaf(-v.w, cy, B0x);
                B0y = fmaf(v.z, cy, B0y); B0y = fmaf(v.w, cx, B0y);
            } else {
                A1x = fmaf(v.x, cx, A1x); A1x = fmaf(-v.y, cy, A1x);
                A1y = fmaf(v.x, cy, A1y); A1y = fmaf(v.y, cx, A1y);
                B1x = fmaf(v.z, cx, B1x); B1x = fmaf(-v.w, cy, B1x);
                B1y = fmaf(v.z, cy, B1y); B1y = fmaf(v.w, cx, B1y);
            }
            float nx = fmaf(cx, wsx, -cy * wsy);
            float ny = fmaf(cx, wsy, cy * wsx);
            cxm[m] = nx; cym[m] = ny;
        }
    }
    float ax0 = A0x + A1x, ay0 = A0y + A1y;
    float ax1 = B0x + B1x, ay1 = B0y + B1y;

    if (q == 0) {  // t = 256 term: omega^{256*a} = conj(omega^{a})
        float4 v = col[256];
        float2 tb = twL[a];
        float ex = tb.x, ey = SIGN * tb.y;
        ax0 = fmaf(v.x, ex, ax0); ax0 = fmaf(-v.y, ey, ax0);
        ay0 = fmaf(v.x, ey, ay0); ay0 = fmaf(v.y, ex, ay0);
        ax1 = fmaf(v.z, ex, ax1); ax1 = fmaf(-v.w, ey, ax1);
        ay1 = fmaf(v.z, ey, ay1); ay1 = fmaf(v.w, ex, ay1);
    } else {
        sacc[q - 1][al] = make_float4(ax0, ay0, ax1, ay1);
    }
    __syncthreads();

    double sum_local = 0.0;
    if (q == 0) {
        #pragma unroll
        for (int r = 0; r < 3; ++r) {
            float4 b = sacc[r][al];
            ax0 += b.x; ay0 += b.y; ax1 += b.z; ay1 += b.w;
        }
        if (MODE < 3) {
            out[(c * NN + bc0) * NN + a] = make_float2(ax0, ay0);
            out[(c * NN + bc1) * NN + a] = make_float2(ax1, ay1);
        } else {
            int jj0 = bc0 + 129; if (jj0 >= NN) jj0 -= NN;
            int jj1 = bc1 + 129; if (jj1 >= NN) jj1 -= NN;
            int ii = a + 129; if (ii >= NN) ii -= NN;
            float m0 = fmaf(ax0, ax0, ay0 * ay0) * invn4;
            float m1 = fmaf(ax1, ax1, ay1 * ay1) * invn4;
            raw[c * PCH + jj0 * PROW + ii] = m0;
            raw[c * PCH + jj1 * PROW + ii] = m1;
            sum_local = (double)m0 + (double)(dupf * m1);
        }
    }

    // ---- a = 256 output (ah==3 blocks only): coeff(t) = conj(omega^t) = (twL[t].x, SIGN*twL[t].y) ----
    if (ah == 3) {
        float c_ = twL[tid].x, s_ = SIGN * twL[tid].y;
        float4 cv = col[tid];
        float tx0 = cv.x * c_ - cv.y * s_;
        float ty0 = cv.x * s_ + cv.y * c_;
        float tx1 = cv.z * c_ - cv.w * s_;
        float ty1 = cv.z * s_ + cv.w * c_;
        if (tid == 0) {
            c_ = twL[256].x; s_ = SIGN * twL[256].y;
            cv = col[256];
            tx0 += cv.x * c_ - cv.y * s_;
            ty0 += cv.x * s_ + cv.y * c_;
            tx1 += cv.z * c_ - cv.w * s_;
            ty1 += cv.z * s_ + cv.w * c_;
        }
        for (int o = 32; o > 0; o >>= 1) {
            tx0 += __shfl_down(tx0, o);
            ty0 += __shfl_down(ty0, o);
            tx1 += __shfl_down(tx1, o);
            ty1 += __shfl_down(ty1, o);
        }
        int wid = tid >> 6;
        if ((tid & 63) == 0) red[wid] = make_float4(tx0, ty0, tx1, ty1);
        __syncthreads();
        if (tid == 0) {
            float Xx0 = red[0].x + red[1].x + red[2].x + red[3].x;
            float Xy0 = red[0].y + red[1].y + red[2].y + red[3].y;
            float Xx1 = red[0].z + red[1].z + red[2].z + red[3].z;
            float Xy1 = red[0].w + red[1].w + red[2].w + red[3].w;
            if (MODE < 3) {
                out[(c * NN + bc0) * NN + 256] = make_float2(Xx0, Xy0);
                out[(c * NN + bc1) * NN + 256] = make_float2(Xx1, Xy1);
            } else {
                int jj0 = bc0 + 129; if (jj0 >= NN) jj0 -= NN;
                int jj1 = bc1 + 129; if (jj1 >= NN) jj1 -= NN;
                float m0 = fmaf(Xx0, Xx0, Xy0 * Xy0) * invn4;
                float m1 = fmaf(Xx1, Xx1, Xy1 * Xy1) * invn4;
                raw[c * PCH + jj0 * PROW + 128] = m0;  // (256+129)%257 == 128
                raw[c * PCH + jj1 * PROW + 128] = m1;
                sum_local += (double)m0 + (double)(dupf * m1);
            }
        }
    }

    if (MODE == 3) {
        // only wave 0 (tids 0..63, q==0) holds nonzero sum_local
        if (tid < 64) {
            double s = sum_local;
            for (int o = 32; o > 0; o >>= 1) s += __shfl_down(s, o);
            if (tid == 0) atomicAdd(&sums[c], s);
        }
    }
}

// ---------------- conv: swizzled flipped-psf LDS, padded img rows, 2y x 8x x (2-3)r per thread ----------------
// out[y][x] = sum_r sum_v img[y+r-128][v] * psf[r][v-x+128];  F[rr][sw(i)] = psf[r0+rr][256-i]
#define CMAP(aL, aH, iv)                                                                                              \
    aL.x = fmaf(iv.x, W1.x, aL.x); aL.x = fmaf(iv.y, W0.w, aL.x); aL.x = fmaf(iv.z, W0.z, aL.x); aL.x = fmaf(iv.w, W0.y, aL.x); \
    aL.y = fmaf(iv.x, W1.y, aL.y); aL.y = fmaf(iv.y, W1.x, aL.y); aL.y = fmaf(iv.z, W0.w, aL.y); aL.y = fmaf(iv.w, W0.z, aL.y); \
    aL.z = fmaf(iv.x, W1.z, aL.z); aL.z = fmaf(iv.y, W1.y, aL.z); aL.z = fmaf(iv.z, W1.x, aL.z); aL.z = fmaf(iv.w, W0.w, aL.z); \
    aL.w = fmaf(iv.x, W1.w, aL.w); aL.w = fmaf(iv.y, W1.z, aL.w); aL.w = fmaf(iv.z, W1.y, aL.w); aL.w = fmaf(iv.w, W1.x, aL.w); \
    aH.x = fmaf(iv.x, W2.x, aH.x); aH.x = fmaf(iv.y, W1.w, aH.x); aH.x = fmaf(iv.z, W1.z, aH.x); aH.x = fmaf(iv.w, W1.y, aH.x); \
    aH.y = fmaf(iv.x, W2.y, aH.y); aH.y = fmaf(iv.y, W2.x, aH.y); aH.y = fmaf(iv.z, W1.w, aH.y); aH.y = fmaf(iv.w, W1.z, aH.y); \
    aH.z = fmaf(iv.x, W2.z, aH.z); aH.z = fmaf(iv.y, W2.y, aH.z); aH.z = fmaf(iv.z, W2.x, aH.z); aH.z = fmaf(iv.w, W1.w, aH.z); \
    aH.w = fmaf(iv.x, W2.w, aH.w); aH.w = fmaf(iv.y, W2.z, aH.w); aH.w = fmaf(iv.z, W2.y, aH.w); aH.w = fmaf(iv.w, W2.x, aH.w);

__global__ __launch_bounds__(256) void k_conv(const float* __restrict__ imgp, const float* __restrict__ psf,
                                              float* __restrict__ part) {
    __shared__ float F[9][FSW];       // flipped+swizzled psf rows r0..r0+8
    __shared__ float simg[16][132];   // img rows ulo..ulo+15, padded stride (zero outside [0,128))
    __shared__ float sacc[3][4][260];
    const int yt = blockIdx.x;   // 0..15
    const int rz = blockIdx.y;   // 0..14
    const int c = blockIdx.z;
    const int y0 = yt * 8;
    const int r0 = 121 - y0 + 9 * rz;   // psf rows r0..r0+8, in [1,255]
    const int tid = threadIdx.x;
    const int tx = tid & 15;
    const int tyb = (tid >> 4) & 3;   // 2 y rows each
    const int rh = tid >> 6;          // rr split: {0,1,2},{3,4},{5,6},{7,8}
    const int x0 = 8 * tx;
    const int ulo = y0 + r0 - 128;

    for (int g = tid; g < 9 * 65; g += 256) {
        int rr = g / 65, q = g - 65 * rr;
        const float* G = psf + c * PCH + (r0 + rr) * PROW + 4 * q;
        float4 A = *(const float4*)G;
        if (q < 64) {
            F[rr][SW(256 - 4 * q)] = A.x;
            F[rr][SW(255 - 4 * q)] = A.y;
            F[rr][SW(254 - 4 * q)] = A.z;
            F[rr][SW(253 - 4 * q)] = A.w;
        } else {
            F[rr][SW(0)] = A.x;
        }
    }
    for (int g = tid; g < 512; g += 256) {
        int rw = g >> 5, q = g & 31;
        int u = ulo + rw;
        float4 v = make_float4(0.f, 0.f, 0.f, 0.f);
        if (u >= 0 && u < 128) v = *(const float4*)(imgp + c * 16384 + u * 128 + 4 * q);
        *(float4*)&simg[rw][4 * q] = v;
    }
    __syncthreads();

    float4 aL0 = make_float4(0.f, 0.f, 0.f, 0.f), aH0 = aL0, aL1 = aL0, aH1 = aL0;
    const int rrbeg = (rh == 0) ? 0 : 2 * rh + 1;
    const int rrend = (rh == 0) ? 3 : 2 * rh + 3;

    for (int rr = rrbeg; rr < rrend; ++rr) {
        const float* Fr = &F[rr][0];
        const int ur = 2 * tyb + rr;
        const float* I0 = &simg[ur][0];
        const float* I1 = &simg[ur + 1][0];
        float4 W1 = *(const float4*)(Fr + SWG(x0 + 128));
        float4 W2 = *(const float4*)(Fr + SWG(x0 + 132));
        #pragma unroll 2
        for (int vb = 0; vb < 128; vb += 4) {
            float4 W0 = *(const float4*)(Fr + SWG(x0 + 124 - vb));
            float4 i0 = *(const float4*)(I0 + vb);
            float4 i1 = *(const float4*)(I1 + vb);
            CMAP(aL0, aH0, i0)
            CMAP(aL1, aH1, i1)
            W2 = W1; W1 = W0;
        }
    }

    if (rh != 0) {
        int s = tid & 63;
        *(float4*)&sacc[rh - 1][0][4 * s] = aL0;
        *(float4*)&sacc[rh - 1][1][4 * s] = aH0;
        *(float4*)&sacc[rh - 1][2][4 * s] = aL1;
        *(float4*)&sacc[rh - 1][3][4 * s] = aH1;
    }
    __syncthreads();
    if (rh == 0) {
        int s = tid;  // 0..63
        #pragma unroll
        for (int r = 0; r < 3; ++r) {
            float4 b0 = *(const float4*)&sacc[r][0][4 * s];
            float4 b1 = *(const float4*)&sacc[r][1][4 * s];
            float4 b2 = *(const float4*)&sacc[r][2][4 * s];
            float4 b3 = *(const float4*)&sacc[r][3][4 * s];
            aL0.x += b0.x; aL0.y += b0.y; aL0.z += b0.z; aL0.w += b0.w;
            aH0.x += b1.x; aH0.y += b1.y; aH0.z += b1.z; aH0.w += b1.w;
            aL1.x += b2.x; aL1.y += b2.y; aL1.z += b2.z; aL1.w += b2.w;
            aH1.x += b3.x; aH1.y += b3.y; aH1.z += b3.z; aH1.w += b3.w;
        }
        const int y = y0 + 2 * tyb;
        float* dst = part + ((rz * 3 + c) * 128 + y) * 128 + x0;
        *(float4*)dst = aL0;
        *(float4*)(dst + 4) = aH0;
        *(float4*)(dst + 128) = aL1;
        *(float4*)(dst + 132) = aH1;
    }
}

// ---------------- final: combine conv partials (gid<49152) + psf normalize (rest) ----------------
__global__ __launch_bounds__(256) void k_final(const float* __restrict__ part, const float* __restrict__ raw,
                                               const double* __restrict__ zs, float* __restrict__ out) {
    int gid = blockIdx.x * 256 + threadIdx.x;
    if (gid < 49152) {
        int c = gid >> 14;
        int r = gid & 16383;
        float s = 0.f;
        #pragma unroll
        for (int rz = 0; rz < NRZ; ++rz) s += part[((rz * 3 + c) * 128 + (r >> 7)) * 128 + (r & 127)];
        float inv = (float)(1.0 / (zs[1 + c] + 1e-7));
        out[r * 3 + c] = s * inv;
    } else {
        int o = gid - 49152;
        if (o < 3 * NN2) {
            int idx = o / 3, c = o - 3 * idx;
            int j = idx / NN, i = idx - NN * j;
            float inv = (float)(1.0 / (zs[1 + c] + 1e-7));
            out[49152 + o] = raw[c * PCH + j * PROW + i] * inv;
        }
    }
}

extern "C" void kernel_launch(void* const* d_in, const int* in_sizes, int n_in,
                              void* d_out, int out_size, void* d_ws, size_t ws_size,
                              hipStream_t stream) {
    const float* img = (const float*)d_in[0];    // (128,128,3) f32
    const float* depth = (const float*)d_in[1];  // (128,128) f32
    float* out = (float*)d_out;                  // 49152 (image) + 198147 (psf)

    char* ws = (char*)d_ws;
    double* zs = (double*)ws;                          // [0]=z1, [1..3]=psf sums
    float2* bufA = (float2*)(ws + 64);                 // 3*NN2 complex
    float2* bufB = bufA + 3 * NN2;                     // 3*NN2 complex
    float* raw = (float*)(bufB + 3 * NN2);             // 3*PCH floats (padded planar |u|^2/N^4)
    float* imgp = raw + 3 * PCH;                       // 3*16384 planar image
    float2* twg = (float2*)(imgp + 3 * 16384);         // 257 twiddles
    float* part = (float*)(ws + 64);                   // aliases bufA+bufB (dead after last dft); NRZ*3*16384 floats

    k_prep<<<194, 256, 0, stream>>>(depth, img, zs, imgp, twg);
    k_dft<-1, 0><<<dim3(4, 129, 3), 256, 0, stream>>>(nullptr, bufA, twg, zs, nullptr, nullptr);
    k_dft<-1, 1><<<dim3(4, 129, 3), 256, 0, stream>>>(bufA, bufB, twg, zs, nullptr, nullptr);
    k_dft< 1, 2><<<dim3(4, 129, 3), 256, 0, stream>>>(bufB, bufA, twg, zs, nullptr, nullptr);
    k_dft< 1, 3><<<dim3(4, 129, 3), 256, 0, stream>>>(bufA, nullptr, twg, zs, raw, zs + 1);
    k_conv<<<dim3(16, NRZ, 3), 256, 0, stream>>>(imgp, raw, part);
    k_final<<<(49152 + 3 * NN2 + 255) / 256, 256, 0, stream>>>(part, raw, zs, out);
}